// Round 9
// baseline (164.510 us; speedup 1.0000x reference)
//
#include <hip/hip_runtime.h>

#define D 64
#define NK 1024
#define QTOTAL 65536
#define NELEM (QTOTAL * D)
#define LOSS_OFF 4194304
#define IDX_OUT_OFF 4194305
#define MARGIN 2.0e-3f

typedef float f32x16 __attribute__((ext_vector_type(16)));
typedef short bf16x8 __attribute__((ext_vector_type(8)));
typedef float f32x4 __attribute__((ext_vector_type(4)));
typedef unsigned int u32;
typedef unsigned short ushort_t;

// ---- ws layout (bytes) ----
#define WS_E2   0          // 1024 f32
#define WS_EH   4096       // 65536 bf16 (hi)
#define WS_EM   135168     // 65536 bf16 (mid)
#define WS_NEED 266240

__device__ __forceinline__ ushort_t f2bf(float f) {
    u32 u = __float_as_uint(f);
    return (ushort_t)((u + 0x7FFFu + ((u >> 16) & 1u)) >> 16);
}
__device__ __forceinline__ float bf2f(ushort_t h) {
    return __uint_as_float(((u32)h) << 16);
}
__device__ __forceinline__ void split8(float4 a, float4 b, bf16x8* h, bf16x8* m) {
    float v[8] = {a.x, a.y, a.z, a.w, b.x, b.y, b.z, b.w};
#pragma unroll
    for (int i = 0; i < 8; ++i) {
        ushort_t hs = f2bf(v[i]);
        ushort_t ms = f2bf(v[i] - bf2f(hs));
        (*h)[i] = (short)hs;
        (*m)[i] = (short)ms;
    }
}

// ---------------- K0: split emb into bf16 hi/mid; e2; zero loss -------------
__global__ __launch_bounds__(256) void vqk0(const float* __restrict__ emb,
                                            u32* __restrict__ eh32, u32* __restrict__ em32,
                                            float* __restrict__ e2,
                                            float* __restrict__ out) {
    int gid = blockIdx.x * 256 + threadIdx.x;   // 128 blocks -> 32768 threads
    float2 v = ((const float2*)emb)[gid];
    ushort_t h0 = f2bf(v.x), h1 = f2bf(v.y);
    ushort_t m0 = f2bf(v.x - bf2f(h0)), m1 = f2bf(v.y - bf2f(h1));
    eh32[gid] = (u32)h0 | ((u32)h1 << 16);
    em32[gid] = (u32)m0 | ((u32)m1 << 16);
    if (gid < NK) {                             // exact f32 |e|^2 (R3 order)
        const float4* e4 = (const float4*)(emb + (long)gid * D);
        float s = 0.f;
#pragma unroll
        for (int i = 0; i < D / 4; ++i) {
            float4 w = e4[i];
            s += w.x * w.x + w.y * w.y + w.z * w.z + w.w * w.w;
        }
        e2[gid] = s;
    }
    if (gid == 0) out[LOSS_OFF] = 0.0f;
}

#define LDB(P) (*(const bf16x8*)(P))

// One 16-code tile vs both query sub-tiles: dot = hh + hm + mh.
#define COMPUTE_TILE(T, BH0, BH1, BM0, BM1) do {                               \
    const int c_ = (T) * 16 + row;                                             \
    const float h_ = 0.5f * e2l[c_];                                           \
    _Pragma("unroll")                                                          \
    for (int s_ = 0; s_ < 2; ++s_) {                                           \
        f32x4 acc = {0.f, 0.f, 0.f, 0.f};                                      \
        acc = __builtin_amdgcn_mfma_f32_16x16x32_bf16(ah[s_][0], BM0, acc, 0, 0, 0); \
        acc = __builtin_amdgcn_mfma_f32_16x16x32_bf16(am[s_][0], BH0, acc, 0, 0, 0); \
        acc = __builtin_amdgcn_mfma_f32_16x16x32_bf16(ah[s_][0], BH0, acc, 0, 0, 0); \
        acc = __builtin_amdgcn_mfma_f32_16x16x32_bf16(ah[s_][1], BM1, acc, 0, 0, 0); \
        acc = __builtin_amdgcn_mfma_f32_16x16x32_bf16(am[s_][1], BH1, acc, 0, 0, 0); \
        acc = __builtin_amdgcn_mfma_f32_16x16x32_bf16(ah[s_][1], BH1, acc, 0, 0, 0); \
        _Pragma("unroll")                                                      \
        for (int r_ = 0; r_ < 4; ++r_) {                                       \
            int sl_ = s_ * 4 + r_;                                             \
            float sd_ = h_ - acc[r_];                                          \
            bool lt_ = sd_ < s1v[sl_];                                         \
            float cd_ = lt_ ? s1v[sl_] : sd_;                                  \
            s2v[sl_] = cd_ < s2v[sl_] ? cd_ : s2v[sl_];                        \
            s1v[sl_] = lt_ ? sd_ : s1v[sl_];                                   \
            i1v[sl_] = lt_ ? c_ : i1v[sl_];                                    \
        }                                                                      \
    }                                                                          \
} while (0)

// ---------------- K1 (mega): coarse MFMA top-2 + in-block rescue + epilogue -
// 512 blocks x 256 thr (2 blocks/CU). Block owns 128 queries (32/wave, 2
// sub-tiles of 16). B-frags double-buffered in registers: tile t+1's loads
// issue before tile t's MFMAs -> L2 latency hidden under compute. idx stays
// in LDS; flagged queries rescued exactly in-block; quantized gather, idx
// write and loss atomic fused here (2 launches total).
__global__ __launch_bounds__(256, 2) void vqk1(const float* __restrict__ x,
                                               const ushort_t* __restrict__ eh,
                                               const ushort_t* __restrict__ em,
                                               const float* __restrict__ e2g,
                                               const float* __restrict__ emb,
                                               float* __restrict__ out) {
    __shared__ float e2l[NK];        // 4 KB
    __shared__ int   idx_l[128];
    __shared__ int   list_l[128];
    __shared__ u32   cnt_l;
    __shared__ float red_s[4];
    __shared__ int   red_i[4];
    __shared__ float lred[4];

    const int tid = threadIdx.x;
    const int l = tid & 63;
    const int w = tid >> 6;
    const int qbase = blockIdx.x * 128;
    const int row = l & 15;
    const int g = l >> 4;
    const int koff = g * 8;

    ((f32x4*)e2l)[tid] = ((const f32x4*)e2g)[tid];
    if (tid == 0) cnt_l = 0;

    // Split this wave's 32 queries into bf16 hi/mid A-frags in-register.
    bf16x8 ah[2][2], am[2][2];
#pragma unroll
    for (int s = 0; s < 2; ++s) {
        const float* xr = x + (long)(qbase + w * 32 + s * 16 + row) * D + koff;
        float4 p0 = ((const float4*)xr)[0];
        float4 p1 = ((const float4*)xr)[1];
        float4 p2 = ((const float4*)(xr + 32))[0];
        float4 p3 = ((const float4*)(xr + 32))[1];
        split8(p0, p1, &ah[s][0], &am[s][0]);
        split8(p2, p3, &ah[s][1], &am[s][1]);
    }
    __syncthreads();

    float s1v[8], s2v[8];
    int i1v[8];
#pragma unroll
    for (int i = 0; i < 8; ++i) { s1v[i] = 3.4e38f; s2v[i] = 3.4e38f; i1v[i] = 0; }

    // ---- main scan, double-buffered prefetch (unroll 2) ----
    long bb = (long)row * D + koff;              // tile 0
    bf16x8 bh0 = LDB(eh + bb), bh1 = LDB(eh + bb + 32);
    bf16x8 bm0 = LDB(em + bb), bm1 = LDB(em + bb + 32);
#pragma unroll 1
    for (int t = 0; t < 64; t += 2) {
        long b1 = bb + 16 * D;                   // tile t+1
        bf16x8 ch0 = LDB(eh + b1), ch1 = LDB(eh + b1 + 32);
        bf16x8 cm0 = LDB(em + b1), cm1 = LDB(em + b1 + 32);
        COMPUTE_TILE(t, bh0, bh1, bm0, bm1);
        long b2 = (t == 62) ? ((long)row * D + koff) : bb + 32 * D;  // tile t+2 (wrap)
        bh0 = LDB(eh + b2); bh1 = LDB(eh + b2 + 32);
        bm0 = LDB(em + b2); bm1 = LDB(em + b2 + 32);
        COMPUTE_TILE(t + 1, ch0, ch1, cm0, cm1);
        bb = b2;
    }

    // merge top-2 across the 16 code-columns (validated R8)
#pragma unroll
    for (int d = 1; d < 16; d <<= 1) {
#pragma unroll
        for (int sl = 0; sl < 8; ++sl) {
            float os1 = __shfl_xor(s1v[sl], d, 64);
            float os2 = __shfl_xor(s2v[sl], d, 64);
            int   oi1 = __shfl_xor(i1v[sl], d, 64);
            float hi = s1v[sl] > os1 ? s1v[sl] : os1;
            float lo2 = s2v[sl] < os2 ? s2v[sl] : os2;
            int ni = (os1 < s1v[sl]) ? oi1
                   : ((os1 == s1v[sl] && oi1 < i1v[sl]) ? oi1 : i1v[sl]);
            s1v[sl] = s1v[sl] < os1 ? s1v[sl] : os1;
            s2v[sl] = hi < lo2 ? hi : lo2;
            i1v[sl] = ni;
        }
    }

    if (row == 0) {
#pragma unroll
        for (int sl = 0; sl < 8; ++sl) {
            int s = sl >> 2, r = sl & 3;
            int ql = w * 32 + s * 16 + g * 4 + r;
            idx_l[ql] = i1v[sl];
            if (s2v[sl] - s1v[sl] <= MARGIN) {
                u32 p = atomicAdd(&cnt_l, 1u);
                list_l[p] = ql;                  // <=128 entries, can't overflow
            }
        }
    }
    __syncthreads();

    // ---- in-block exact f32 rescue (expected ~0.3 queries/block) ----
    const u32 nr = cnt_l;
    for (u32 i = 0; i < nr; ++i) {
        int ql = list_l[i];
        int q = qbase + ql;
        float4 xv[16];
        const float4* xp = (const float4*)(x + (long)q * D);
#pragma unroll
        for (int k = 0; k < 16; ++k) xv[k] = xp[k];
        float best = 3.4e38f; int bi = 0;
#pragma unroll
        for (int j = 0; j < 4; ++j) {
            int c = tid * 4 + j;                 // ascending with tid
            const float4* ep = (const float4*)(emb + (long)c * D);
            float a0 = 0.f, a1 = 0.f, a2 = 0.f, a3 = 0.f;
#pragma unroll
            for (int k = 0; k < 16; ++k) {
                float4 e = ep[k];
                a0 = fmaf(e.x, xv[k].x, a0); a1 = fmaf(e.y, xv[k].y, a1);
                a2 = fmaf(e.z, xv[k].z, a2); a3 = fmaf(e.w, xv[k].w, a3);
            }
            float s = 0.5f * e2l[c] - ((a0 + a1) + (a2 + a3));
            if (s < best) { best = s; bi = c; }
        }
#pragma unroll
        for (int off = 32; off > 0; off >>= 1) {
            float ob = __shfl_down(best, off, 64);
            int   oi = __shfl_down(bi, off, 64);
            if (ob < best || (ob == best && oi < bi)) { best = ob; bi = oi; }
        }
        if (l == 0) { red_s[w] = best; red_i[w] = bi; }
        __syncthreads();
        if (tid == 0) {
            float b = red_s[0]; int c = red_i[0];
#pragma unroll
            for (int wv = 1; wv < 4; ++wv)
                if (red_s[wv] < b) { b = red_s[wv]; c = red_i[wv]; }  // wave asc = code asc
            idx_l[ql] = c;
        }
        __syncthreads();
    }

    // ---- epilogue: gather quantized, write idx, loss partial ----
    {
        int ql = tid >> 1;                       // 2 threads per query
        int part = tid & 1;                      // 32 floats each
        int q = qbase + ql;
        int idx = idx_l[ql];
        const float4* xp = (const float4*)(x + (long)q * D + part * 32);
        const float4* ep = (const float4*)(emb + (long)idx * D + part * 32);
        float4* op = (float4*)(out + (long)q * D + part * 32);
        float ls = 0.f;
#pragma unroll
        for (int k = 0; k < 8; ++k) {
            float4 xx = xp[k];
            float4 ev = ep[k];
            op[k] = ev;
            float dx = ev.x - xx.x, dy = ev.y - xx.y, dz = ev.z - xx.z, dw = ev.w - xx.w;
            ls += dx * dx + dy * dy + dz * dz + dw * dw;
        }
        if (part == 0) out[IDX_OUT_OFF + q] = (float)idx;
#pragma unroll
        for (int off = 32; off > 0; off >>= 1) ls += __shfl_down(ls, off, 64);
        if (l == 0) lred[w] = ls;
        __syncthreads();
        if (tid == 0)
            atomicAdd(&out[LOSS_OFF],
                      (lred[0] + lred[1] + lred[2] + lred[3]) * (0.25f / (float)NELEM));
    }
}

// ================== R3 fallback (ws too small) ==============================
#define FDO_CHUNK(B, K) \
    aA0 = fmaf(B[0],  xA[4*K+0].x, aA0); aA1 = fmaf(B[1],  xA[4*K+0].y, aA1); \
    aA2 = fmaf(B[2],  xA[4*K+0].z, aA2); aA3 = fmaf(B[3],  xA[4*K+0].w, aA3); \
    aA0 = fmaf(B[4],  xA[4*K+1].x, aA0); aA1 = fmaf(B[5],  xA[4*K+1].y, aA1); \
    aA2 = fmaf(B[6],  xA[4*K+1].z, aA2); aA3 = fmaf(B[7],  xA[4*K+1].w, aA3); \
    aA0 = fmaf(B[8],  xA[4*K+2].x, aA0); aA1 = fmaf(B[9],  xA[4*K+2].y, aA1); \
    aA2 = fmaf(B[10], xA[4*K+2].z, aA2); aA3 = fmaf(B[11], xA[4*K+2].w, aA3); \
    aA0 = fmaf(B[12], xA[4*K+3].x, aA0); aA1 = fmaf(B[13], xA[4*K+3].y, aA1); \
    aA2 = fmaf(B[14], xA[4*K+3].z, aA2); aA3 = fmaf(B[15], xA[4*K+3].w, aA3); \
    aB0 = fmaf(B[0],  xB[4*K+0].x, aB0); aB1 = fmaf(B[1],  xB[4*K+0].y, aB1); \
    aB2 = fmaf(B[2],  xB[4*K+0].z, aB2); aB3 = fmaf(B[3],  xB[4*K+0].w, aB3); \
    aB0 = fmaf(B[4],  xB[4*K+1].x, aB0); aB1 = fmaf(B[5],  xB[4*K+1].y, aB1); \
    aB2 = fmaf(B[6],  xB[4*K+1].z, aB2); aB3 = fmaf(B[7],  xB[4*K+1].w, aB3); \
    aB0 = fmaf(B[8],  xB[4*K+2].x, aB0); aB1 = fmaf(B[9],  xB[4*K+2].y, aB1); \
    aB2 = fmaf(B[10], xB[4*K+2].z, aB2); aB3 = fmaf(B[11], xB[4*K+2].w, aB3); \
    aB0 = fmaf(B[12], xB[4*K+3].x, aB0); aB1 = fmaf(B[13], xB[4*K+3].y, aB1); \
    aB2 = fmaf(B[14], xB[4*K+3].z, aB2); aB3 = fmaf(B[15], xB[4*K+3].w, aB3);

__global__ __launch_bounds__(256) void vq_e2f(const float* __restrict__ emb,
                                              float* __restrict__ e2,
                                              float* __restrict__ out) {
    int k = blockIdx.x * blockDim.x + threadIdx.x;
    if (k == 0) out[LOSS_OFF] = 0.0f;
    if (k < NK) {
        const float4* e4 = (const float4*)(emb + k * D);
        float s = 0.f;
#pragma unroll
        for (int i = 0; i < D / 4; ++i) {
            float4 v = e4[i];
            s += v.x * v.x + v.y * v.y + v.z * v.z + v.w * v.w;
        }
        e2[k] = s;
    }
}

__global__ __launch_bounds__(256, 2) void vq_mainf(const float* __restrict__ x,
                                                   const float* __restrict__ emb,
                                                   const float* __restrict__ e2g,
                                                   float* __restrict__ out) {
    __shared__ float e2l[NK];
    __shared__ float sm_s[512];
    __shared__ int   sm_c[512];
    const int tid = threadIdx.x;
    const int l = tid & 63;
    const int w = tid >> 6;
    const int qbase = blockIdx.x * 128;
    ((float4*)e2l)[tid] = ((const float4*)e2g)[tid];
    float4 xA[16], xB[16];
    const float4* xpA = (const float4*)(x + (long)(qbase + l) * D);
    const float4* xpB = (const float4*)(x + (long)(qbase + 64 + l) * D);
#pragma unroll
    for (int i = 0; i < 16; ++i) { xA[i] = xpA[i]; xB[i] = xpB[i]; }
    __syncthreads();
    const int code0 = __builtin_amdgcn_readfirstlane(w << 8);
    const float* ep0 = emb + (long)code0 * D;
    float bestA = 3.4e38f, bestB = 3.4e38f;
    int idxA = 0, idxB = 0;
#pragma unroll 1
    for (int g = 0; g < 256; ++g) {
        const float* ep = ep0 + g * D;
        f32x16 b0, b1, b2, b3;
        asm volatile(
            "s_load_dwordx16 %0, %4, 0x0\n\t"
            "s_load_dwordx16 %1, %4, 0x40\n\t"
            "s_load_dwordx16 %2, %4, 0x80\n\t"
            "s_load_dwordx16 %3, %4, 0xC0\n\t"
            "s_waitcnt lgkmcnt(0)"
            : "=s"(b0), "=s"(b1), "=s"(b2), "=s"(b3) : "s"(ep));
        float aA0 = 0.f, aA1 = 0.f, aA2 = 0.f, aA3 = 0.f;
        float aB0 = 0.f, aB1 = 0.f, aB2 = 0.f, aB3 = 0.f;
        FDO_CHUNK(b0, 0) FDO_CHUNK(b1, 1) FDO_CHUNK(b2, 2) FDO_CHUNK(b3, 3)
        float dotA = (aA0 + aA1) + (aA2 + aA3);
        float dotB = (aB0 + aB1) + (aB2 + aB3);
        float e2c = e2l[code0 + g];
        float sA = 0.5f * e2c - dotA;
        float sB = 0.5f * e2c - dotB;
        int code = code0 + g;
        bool lt;
        lt = sA < bestA; bestA = lt ? sA : bestA; idxA = lt ? code : idxA;
        lt = sB < bestB; bestB = lt ? sB : bestB; idxB = lt ? code : idxB;
    }
    sm_s[w * 128 + l] = bestA;      sm_c[w * 128 + l] = idxA;
    sm_s[w * 128 + 64 + l] = bestB; sm_c[w * 128 + 64 + l] = idxB;
    __syncthreads();
    if (tid < 128) {
        float bs = sm_s[tid]; int bc = sm_c[tid];
#pragma unroll
        for (int wv = 1; wv < 4; ++wv) {
            float s = sm_s[wv * 128 + tid]; int c = sm_c[wv * 128 + tid];
            if (s < bs) { bs = s; bc = c; }
        }
        const int q = qbase + tid;
        out[IDX_OUT_OFF + q] = (float)bc;
        const float4* eb = (const float4*)(emb + (long)bc * D);
        const float4* xq = (const float4*)(x + (long)q * D);
        float4* oq = (float4*)(out + (long)q * D);
        float lsum = 0.f;
#pragma unroll
        for (int i = 0; i < 16; ++i) {
            float4 e = eb[i]; float4 xx = xq[i];
            oq[i] = e;
            float dx = e.x - xx.x, dy = e.y - xx.y, dz = e.z - xx.z, dw = e.w - xx.w;
            lsum += dx * dx + dy * dy + dz * dz + dw * dw;
        }
#pragma unroll
        for (int o = 32; o > 0; o >>= 1) lsum += __shfl_down(lsum, o, 64);
        if ((tid & 63) == 0) atomicAdd(&out[LOSS_OFF], lsum * (0.25f / (float)NELEM));
    }
}

extern "C" void kernel_launch(void* const* d_in, const int* in_sizes, int n_in,
                              void* d_out, int out_size, void* d_ws, size_t ws_size,
                              hipStream_t stream) {
    const float* x   = (const float*)d_in[0];
    const float* emb = (const float*)d_in[1];
    float* out = (float*)d_out;
    char* ws = (char*)d_ws;

    if (ws_size < (size_t)WS_NEED) {           // fallback: proven R3 path
        float* e2 = (float*)ws;
        vq_e2f<<<4, 256, 0, stream>>>(emb, e2, out);
        vq_mainf<<<QTOTAL / 128, 256, 0, stream>>>(x, emb, e2, out);
        return;
    }

    float* e2    = (float*)(ws + WS_E2);
    ushort_t* eh = (ushort_t*)(ws + WS_EH);
    ushort_t* em = (ushort_t*)(ws + WS_EM);

    vqk0<<<128, 256, 0, stream>>>(emb, (u32*)eh, (u32*)em, e2, out);
    vqk1<<<512, 256, 0, stream>>>(x, eh, em, e2, emb, out);
}

// Round 10
// 159.718 us; speedup vs baseline: 1.0300x; 1.0300x over previous
//
#include <hip/hip_runtime.h>

#define D 64
#define NK 1024
#define QTOTAL 65536
#define NELEM (QTOTAL * D)
#define LOSS_OFF 4194304
#define IDX_OUT_OFF 4194305
#define CAPQ 16384
#define MARGIN 2.0e-3f

typedef float f32x16 __attribute__((ext_vector_type(16)));
typedef short bf16x8 __attribute__((ext_vector_type(8)));
typedef float f32x4 __attribute__((ext_vector_type(4)));
typedef unsigned int u32;
typedef unsigned short ushort_t;

// ---- ws layout (bytes) ----
#define WS_E2   0          // 1024 f32
#define WS_EH   4096       // 65536 bf16 (hi)
#define WS_EM   135168     // 65536 bf16 (mid)
#define WS_CNT  266240     // u32 (+pad)
#define WS_LIST 266496     // 16384 i32
#define WS_NEED 332032

__device__ __forceinline__ ushort_t f2bf(float f) {
    u32 u = __float_as_uint(f);
    return (ushort_t)((u + 0x7FFFu + ((u >> 16) & 1u)) >> 16);
}
__device__ __forceinline__ float bf2f(ushort_t h) {
    return __uint_as_float(((u32)h) << 16);
}
__device__ __forceinline__ void split8(float4 a, float4 b, bf16x8* h, bf16x8* m) {
    float v[8] = {a.x, a.y, a.z, a.w, b.x, b.y, b.z, b.w};
#pragma unroll
    for (int i = 0; i < 8; ++i) {
        ushort_t hs = f2bf(v[i]);
        ushort_t ms = f2bf(v[i] - bf2f(hs));
        (*h)[i] = (short)hs;
        (*m)[i] = (short)ms;
    }
}

// ---------------- K0: split emb into bf16 hi/mid; e2; zero loss+cnt ---------
__global__ __launch_bounds__(256) void vqk0(const float* __restrict__ emb,
                                            u32* __restrict__ eh32, u32* __restrict__ em32,
                                            float* __restrict__ e2, u32* __restrict__ cnt,
                                            float* __restrict__ out) {
    int gid = blockIdx.x * 256 + threadIdx.x;   // 128 blocks -> 32768 threads
    float2 v = ((const float2*)emb)[gid];
    ushort_t h0 = f2bf(v.x), h1 = f2bf(v.y);
    ushort_t m0 = f2bf(v.x - bf2f(h0)), m1 = f2bf(v.y - bf2f(h1));
    eh32[gid] = (u32)h0 | ((u32)h1 << 16);
    em32[gid] = (u32)m0 | ((u32)m1 << 16);
    if (gid < NK) {                             // exact f32 |e|^2 (R3 order)
        const float4* e4 = (const float4*)(emb + (long)gid * D);
        float s = 0.f;
#pragma unroll
        for (int i = 0; i < D / 4; ++i) {
            float4 w = e4[i];
            s += w.x * w.x + w.y * w.y + w.z * w.z + w.w * w.w;
        }
        e2[gid] = s;
    }
    if (gid == 0) { out[LOSS_OFF] = 0.0f; *cnt = 0; }
}

#define LDB(P) (*(const bf16x8*)(P))

// One 16-code tile vs FOUR query sub-tiles (wave owns 64 queries).
// dot = hh + hm + mh; top-2 via min/med3 (5 VALU per slot).
#define COMPUTE_TILE4(T, BH0, BH1, BM0, BM1) do {                              \
    const int c_ = (T) * 16 + row;                                             \
    const float h_ = 0.5f * e2l[c_];                                           \
    _Pragma("unroll")                                                          \
    for (int s_ = 0; s_ < 4; ++s_) {                                           \
        f32x4 acc = {0.f, 0.f, 0.f, 0.f};                                      \
        acc = __builtin_amdgcn_mfma_f32_16x16x32_bf16(ah[s_][0], BM0, acc, 0, 0, 0); \
        acc = __builtin_amdgcn_mfma_f32_16x16x32_bf16(am[s_][0], BH0, acc, 0, 0, 0); \
        acc = __builtin_amdgcn_mfma_f32_16x16x32_bf16(ah[s_][0], BH0, acc, 0, 0, 0); \
        acc = __builtin_amdgcn_mfma_f32_16x16x32_bf16(ah[s_][1], BM1, acc, 0, 0, 0); \
        acc = __builtin_amdgcn_mfma_f32_16x16x32_bf16(am[s_][1], BH1, acc, 0, 0, 0); \
        acc = __builtin_amdgcn_mfma_f32_16x16x32_bf16(ah[s_][1], BH1, acc, 0, 0, 0); \
        _Pragma("unroll")                                                      \
        for (int r_ = 0; r_ < 4; ++r_) {                                       \
            int sl_ = s_ * 4 + r_;                                             \
            float sd_ = h_ - acc[r_];                                          \
            float ns2_ = fminf(fmaxf(sd_, s1v[sl_]), s2v[sl_]);   /* med3 */   \
            bool lt_ = sd_ < s1v[sl_];                                         \
            i1v[sl_] = lt_ ? c_ : i1v[sl_];                                    \
            s1v[sl_] = fminf(sd_, s1v[sl_]);                                   \
            s2v[sl_] = ns2_;                                                   \
        }                                                                      \
    }                                                                          \
} while (0)

// ---------------- K1: coarse MFMA top-2 (64 q/wave) + streaming epilogue ----
// 256 blocks x 256 thr (1 block/CU, 1 wave/SIMD). Wave owns 64 queries (4
// MFMA sub-tiles) -> total B-traffic halves vs 32 q/wave (1024 waves x 512 KB
// = 2 MB/CU, ~15 us floor). B-frags register double-buffered: tile t+1 loads
// issue before tile t's 24 MFMAs (~350 cyc > L2 latency). Flagged queries
// (top-2 gap <= MARGIN) recorded for the exact fix-up kernel.
__global__ __launch_bounds__(256, 1) void vqk1(const float* __restrict__ x,
                                               const ushort_t* __restrict__ eh,
                                               const ushort_t* __restrict__ em,
                                               const float* __restrict__ e2g,
                                               const float* __restrict__ emb,
                                               u32* __restrict__ cnt,
                                               int* __restrict__ list,
                                               float* __restrict__ out) {
    __shared__ float e2l[NK];        // 4 KB
    __shared__ int   idx_l[256];     // 1 KB

    const int tid = threadIdx.x;
    const int l = tid & 63;
    const int w = tid >> 6;
    const int qbase = blockIdx.x * 256;
    const int wb = qbase + w * 64;   // wave's first query
    const int row = l & 15;
    const int g = l >> 4;
    const int koff = g * 8;

    ((f32x4*)e2l)[tid] = ((const f32x4*)e2g)[tid];

    // Split this wave's 64 queries into bf16 hi/mid A-frags in-register.
    bf16x8 ah[4][2], am[4][2];
#pragma unroll
    for (int s = 0; s < 4; ++s) {
        const float* xr = x + (long)(wb + s * 16 + row) * D + koff;
        float4 p0 = ((const float4*)xr)[0];
        float4 p1 = ((const float4*)xr)[1];
        float4 p2 = ((const float4*)(xr + 32))[0];
        float4 p3 = ((const float4*)(xr + 32))[1];
        split8(p0, p1, &ah[s][0], &am[s][0]);
        split8(p2, p3, &ah[s][1], &am[s][1]);
    }
    __syncthreads();

    float s1v[16], s2v[16];
    int i1v[16];
#pragma unroll
    for (int i = 0; i < 16; ++i) { s1v[i] = 3.4e38f; s2v[i] = 3.4e38f; i1v[i] = 0; }

    // ---- main scan, register double-buffer (R9-validated structure) ----
    long bb = (long)row * D + koff;              // tile 0
    bf16x8 bh0 = LDB(eh + bb), bh1 = LDB(eh + bb + 32);
    bf16x8 bm0 = LDB(em + bb), bm1 = LDB(em + bb + 32);
#pragma unroll 1
    for (int t = 0; t < 64; t += 2) {
        long b1 = bb + 16 * D;                   // tile t+1
        bf16x8 ch0 = LDB(eh + b1), ch1 = LDB(eh + b1 + 32);
        bf16x8 cm0 = LDB(em + b1), cm1 = LDB(em + b1 + 32);
        COMPUTE_TILE4(t, bh0, bh1, bm0, bm1);
        long b2 = (t == 62) ? ((long)row * D + koff) : bb + 32 * D;  // wrap
        bh0 = LDB(eh + b2); bh1 = LDB(eh + b2 + 32);
        bm0 = LDB(em + b2); bm1 = LDB(em + b2 + 32);
        COMPUTE_TILE4(t + 1, ch0, ch1, cm0, cm1);
        bb = b2;
    }

    // merge top-2 across the 16 code-columns; lowest index wins exact ties.
#pragma unroll
    for (int d = 1; d < 16; d <<= 1) {
#pragma unroll
        for (int sl = 0; sl < 16; ++sl) {
            float os1 = __shfl_xor(s1v[sl], d, 64);
            float os2 = __shfl_xor(s2v[sl], d, 64);
            int   oi1 = __shfl_xor(i1v[sl], d, 64);
            float hi = s1v[sl] > os1 ? s1v[sl] : os1;
            float lo2 = s2v[sl] < os2 ? s2v[sl] : os2;
            int ni = (os1 < s1v[sl]) ? oi1
                   : ((os1 == s1v[sl] && oi1 < i1v[sl]) ? oi1 : i1v[sl]);
            s1v[sl] = s1v[sl] < os1 ? s1v[sl] : os1;
            s2v[sl] = hi < lo2 ? hi : lo2;
            i1v[sl] = ni;
        }
    }

    if (row == 0) {
#pragma unroll
        for (int sl = 0; sl < 16; ++sl) {
            int s = sl >> 2, r = sl & 3;
            int ql = w * 64 + s * 16 + g * 4 + r;
            idx_l[ql] = i1v[sl];
            if (s2v[sl] - s1v[sl] <= MARGIN) {
                u32 p = atomicAdd(cnt, 1u);
                if (p < CAPQ) list[p] = qbase + ql;
            }
        }
    }
    __syncthreads();

    // ---- streaming epilogue: idx write, gather quantized, loss partial ----
    out[IDX_OUT_OFF + wb + l] = (float)idx_l[w * 64 + l];

    const f32x4* x4 = (const f32x4*)(x + (long)wb * D);
    const f32x4* e4 = (const f32x4*)emb;
    f32x4* o4 = (f32x4*)(out + (long)wb * D);
    float ls = 0.f;
#pragma unroll 1
    for (int k = 0; k < 16; ++k) {
        int j = l + 64 * k;                      // float4 slot in wave's 4 KB
        int ql = (l >> 4) + 4 * k;               // local query for this slot
        int col = l & 15;                        // float4 column within row
        int idx = idx_l[w * 64 + ql];
        f32x4 xv = x4[j];
        f32x4 ev = e4[idx * 16 + col];           // 16 lanes same row: coalesced
        o4[j] = ev;
        f32x4 dd = ev - xv;
        ls += dd[0] * dd[0] + dd[1] * dd[1] + dd[2] * dd[2] + dd[3] * dd[3];
    }
#pragma unroll
    for (int off = 32; off > 0; off >>= 1) ls += __shfl_down(ls, off, 64);
    if (l == 0) atomicAdd(&out[LOSS_OFF], ls * (0.25f / (float)NELEM));
}

// ---------------- K2: exact rescue fix-up (one wave per flagged query) ------
// Exact f32 re-scan; if argmin differs from coarse: rewrite row, idx, and
// patch loss with the exact delta.
__global__ __launch_bounds__(64) void vqk2(const float* __restrict__ x,
                                           const float* __restrict__ emb,
                                           const float* __restrict__ e2,
                                           const int* __restrict__ list,
                                           const u32* __restrict__ cnt,
                                           float* __restrict__ out) {
    u32 n = *cnt; if (n > CAPQ) n = CAPQ;
    const int l = threadIdx.x;
    for (u32 f = blockIdx.x; f < n; f += gridDim.x) {
        int q = list[f];
        float4 xv[16];
        const float4* xp = (const float4*)(x + (long)q * D);
#pragma unroll
        for (int i = 0; i < 16; ++i) xv[i] = xp[i];
        float best = 3.4e38f; int bi = 0;
#pragma unroll 1
        for (int i = 0; i < 16; ++i) {
            int c = l * 16 + i;                  // lane covers [l*16, l*16+16)
            const float4* ep = (const float4*)(emb + (long)c * D);
            float a0 = 0.f, a1 = 0.f, a2 = 0.f, a3 = 0.f;
#pragma unroll
            for (int k = 0; k < 16; ++k) {
                float4 e = ep[k];
                a0 = fmaf(e.x, xv[k].x, a0); a1 = fmaf(e.y, xv[k].y, a1);
                a2 = fmaf(e.z, xv[k].z, a2); a3 = fmaf(e.w, xv[k].w, a3);
            }
            float s = 0.5f * e2[c] - ((a0 + a1) + (a2 + a3));
            if (s < best) { best = s; bi = c; }  // ascending c: first-min
        }
#pragma unroll
        for (int off = 32; off > 0; off >>= 1) {
            float ob = __shfl_down(best, off, 64);
            int   oi = __shfl_down(bi, off, 64);
            if (ob < best || (ob == best && oi < bi)) { best = ob; bi = oi; }
        }
        bi = __shfl(bi, 0, 64);
        int ci = (int)out[IDX_OUT_OFF + q];      // coarse pick
        if (bi != ci) {
            float xl = x[(long)q * D + l];
            float en = emb[(long)bi * D + l];
            float eo = emb[(long)ci * D + l];
            out[(long)q * D + l] = en;
            float dn = (en - xl) * (en - xl);
            float dol = (eo - xl) * (eo - xl);
            float dd = dn - dol;
#pragma unroll
            for (int off = 32; off > 0; off >>= 1) dd += __shfl_down(dd, off, 64);
            if (l == 0) {
                out[IDX_OUT_OFF + q] = (float)bi;
                atomicAdd(&out[LOSS_OFF], dd * (0.25f / (float)NELEM));
            }
        }
    }
}

// ================== R3 fallback (ws too small) ==============================
#define FDO_CHUNK(B, K) \
    aA0 = fmaf(B[0],  xA[4*K+0].x, aA0); aA1 = fmaf(B[1],  xA[4*K+0].y, aA1); \
    aA2 = fmaf(B[2],  xA[4*K+0].z, aA2); aA3 = fmaf(B[3],  xA[4*K+0].w, aA3); \
    aA0 = fmaf(B[4],  xA[4*K+1].x, aA0); aA1 = fmaf(B[5],  xA[4*K+1].y, aA1); \
    aA2 = fmaf(B[6],  xA[4*K+1].z, aA2); aA3 = fmaf(B[7],  xA[4*K+1].w, aA3); \
    aA0 = fmaf(B[8],  xA[4*K+2].x, aA0); aA1 = fmaf(B[9],  xA[4*K+2].y, aA1); \
    aA2 = fmaf(B[10], xA[4*K+2].z, aA2); aA3 = fmaf(B[11], xA[4*K+2].w, aA3); \
    aA0 = fmaf(B[12], xA[4*K+3].x, aA0); aA1 = fmaf(B[13], xA[4*K+3].y, aA1); \
    aA2 = fmaf(B[14], xA[4*K+3].z, aA2); aA3 = fmaf(B[15], xA[4*K+3].w, aA3); \
    aB0 = fmaf(B[0],  xB[4*K+0].x, aB0); aB1 = fmaf(B[1],  xB[4*K+0].y, aB1); \
    aB2 = fmaf(B[2],  xB[4*K+0].z, aB2); aB3 = fmaf(B[3],  xB[4*K+0].w, aB3); \
    aB0 = fmaf(B[4],  xB[4*K+1].x, aB0); aB1 = fmaf(B[5],  xB[4*K+1].y, aB1); \
    aB2 = fmaf(B[6],  xB[4*K+1].z, aB2); aB3 = fmaf(B[7],  xB[4*K+1].w, aB3); \
    aB0 = fmaf(B[8],  xB[4*K+2].x, aB0); aB1 = fmaf(B[9],  xB[4*K+2].y, aB1); \
    aB2 = fmaf(B[10], xB[4*K+2].z, aB2); aB2 = fmaf(B[11], xB[4*K+2].w, aB2); \
    aB0 = fmaf(B[12], xB[4*K+3].x, aB0); aB1 = fmaf(B[13], xB[4*K+3].y, aB1); \
    aB2 = fmaf(B[14], xB[4*K+3].z, aB2); aB3 = fmaf(B[15], xB[4*K+3].w, aB3);

__global__ __launch_bounds__(256) void vq_e2f(const float* __restrict__ emb,
                                              float* __restrict__ e2,
                                              float* __restrict__ out) {
    int k = blockIdx.x * blockDim.x + threadIdx.x;
    if (k == 0) out[LOSS_OFF] = 0.0f;
    if (k < NK) {
        const float4* e4 = (const float4*)(emb + k * D);
        float s = 0.f;
#pragma unroll
        for (int i = 0; i < D / 4; ++i) {
            float4 v = e4[i];
            s += v.x * v.x + v.y * v.y + v.z * v.z + v.w * v.w;
        }
        e2[k] = s;
    }
}

__global__ __launch_bounds__(256, 2) void vq_mainf(const float* __restrict__ x,
                                                   const float* __restrict__ emb,
                                                   const float* __restrict__ e2g,
                                                   float* __restrict__ out) {
    __shared__ float e2l[NK];
    __shared__ float sm_s[512];
    __shared__ int   sm_c[512];
    const int tid = threadIdx.x;
    const int l = tid & 63;
    const int w = tid >> 6;
    const int qbase = blockIdx.x * 128;
    ((float4*)e2l)[tid] = ((const float4*)e2g)[tid];
    float4 xA[16], xB[16];
    const float4* xpA = (const float4*)(x + (long)(qbase + l) * D);
    const float4* xpB = (const float4*)(x + (long)(qbase + 64 + l) * D);
#pragma unroll
    for (int i = 0; i < 16; ++i) { xA[i] = xpA[i]; xB[i] = xpB[i]; }
    __syncthreads();
    const int code0 = __builtin_amdgcn_readfirstlane(w << 8);
    const float* ep0 = emb + (long)code0 * D;
    float bestA = 3.4e38f, bestB = 3.4e38f;
    int idxA = 0, idxB = 0;
#pragma unroll 1
    for (int g = 0; g < 256; ++g) {
        const float* ep = ep0 + g * D;
        f32x16 b0, b1, b2, b3;
        asm volatile(
            "s_load_dwordx16 %0, %4, 0x0\n\t"
            "s_load_dwordx16 %1, %4, 0x40\n\t"
            "s_load_dwordx16 %2, %4, 0x80\n\t"
            "s_load_dwordx16 %3, %4, 0xC0\n\t"
            "s_waitcnt lgkmcnt(0)"
            : "=s"(b0), "=s"(b1), "=s"(b2), "=s"(b3) : "s"(ep));
        float aA0 = 0.f, aA1 = 0.f, aA2 = 0.f, aA3 = 0.f;
        float aB0 = 0.f, aB1 = 0.f, aB2 = 0.f, aB3 = 0.f;
        FDO_CHUNK(b0, 0) FDO_CHUNK(b1, 1) FDO_CHUNK(b2, 2) FDO_CHUNK(b3, 3)
        float dotA = (aA0 + aA1) + (aA2 + aA3);
        float dotB = (aB0 + aB1) + (aB2 + aB3);
        float e2c = e2l[code0 + g];
        float sA = 0.5f * e2c - dotA;
        float sB = 0.5f * e2c - dotB;
        int code = code0 + g;
        bool lt;
        lt = sA < bestA; bestA = lt ? sA : bestA; idxA = lt ? code : idxA;
        lt = sB < bestB; bestB = lt ? sB : bestB; idxB = lt ? code : idxB;
    }
    sm_s[w * 128 + l] = bestA;      sm_c[w * 128 + l] = idxA;
    sm_s[w * 128 + 64 + l] = bestB; sm_c[w * 128 + 64 + l] = idxB;
    __syncthreads();
    if (tid < 128) {
        float bs = sm_s[tid]; int bc = sm_c[tid];
#pragma unroll
        for (int wv = 1; wv < 4; ++wv) {
            float s = sm_s[wv * 128 + tid]; int c = sm_c[wv * 128 + tid];
            if (s < bs) { bs = s; bc = c; }
        }
        const int q = qbase + tid;
        out[IDX_OUT_OFF + q] = (float)bc;
        const float4* eb = (const float4*)(emb + (long)bc * D);
        const float4* xq = (const float4*)(x + (long)q * D);
        float4* oq = (float4*)(out + (long)q * D);
        float lsum = 0.f;
#pragma unroll
        for (int i = 0; i < 16; ++i) {
            float4 e = eb[i]; float4 xx = xq[i];
            oq[i] = e;
            float dx = e.x - xx.x, dy = e.y - xx.y, dz = e.z - xx.z, dw = e.w - xx.w;
            lsum += dx * dx + dy * dy + dz * dz + dw * dw;
        }
#pragma unroll
        for (int o = 32; o > 0; o >>= 1) lsum += __shfl_down(lsum, o, 64);
        if ((tid & 63) == 0) atomicAdd(&out[LOSS_OFF], lsum * (0.25f / (float)NELEM));
    }
}

extern "C" void kernel_launch(void* const* d_in, const int* in_sizes, int n_in,
                              void* d_out, int out_size, void* d_ws, size_t ws_size,
                              hipStream_t stream) {
    const float* x   = (const float*)d_in[0];
    const float* emb = (const float*)d_in[1];
    float* out = (float*)d_out;
    char* ws = (char*)d_ws;

    if (ws_size < (size_t)WS_NEED) {           // fallback: proven R3 path
        float* e2 = (float*)ws;
        vq_e2f<<<4, 256, 0, stream>>>(emb, e2, out);
        vq_mainf<<<QTOTAL / 128, 256, 0, stream>>>(x, emb, e2, out);
        return;
    }

    float* e2    = (float*)(ws + WS_E2);
    ushort_t* eh = (ushort_t*)(ws + WS_EH);
    ushort_t* em = (ushort_t*)(ws + WS_EM);
    u32* cnt     = (u32*)(ws + WS_CNT);
    int* list    = (int*)(ws + WS_LIST);

    vqk0<<<128, 256, 0, stream>>>(emb, (u32*)eh, (u32*)em, e2, cnt, out);
    vqk1<<<QTOTAL / 256, 256, 0, stream>>>(x, eh, em, e2, emb, cnt, list, out);
    vqk2<<<256, 64, 0, stream>>>(x, emb, e2, list, cnt, out);
}

// Round 11
// 126.542 us; speedup vs baseline: 1.3000x; 1.2622x over previous
//
#include <hip/hip_runtime.h>

#define D 64
#define NK 1024
#define QTOTAL 65536
#define NELEM (QTOTAL * D)
#define LOSS_OFF 4194304
#define IDX_OUT_OFF 4194305
#define CAPQ 16384
#define MARGIN 2.0e-3f

typedef float f32x16 __attribute__((ext_vector_type(16)));
typedef short bf16x8 __attribute__((ext_vector_type(8)));
typedef float f32x4 __attribute__((ext_vector_type(4)));
typedef unsigned int u32;
typedef unsigned short ushort_t;

// ---- ws layout (bytes) ----
#define WS_E2   0          // 1024 f32
#define WS_B    4096       // 256 KB permuted bf16 codebook: [tile][H0|H1|M0|M1][lane][8]
#define WS_CNT  266240     // u32 (+pad)
#define WS_LIST 266496     // 16384 i32
#define WS_NEED 332032

__device__ __forceinline__ ushort_t f2bf(float f) {
    u32 u = __float_as_uint(f);
    return (ushort_t)((u + 0x7FFFu + ((u >> 16) & 1u)) >> 16);
}
__device__ __forceinline__ float bf2f(ushort_t h) {
    return __uint_as_float(((u32)h) << 16);
}

// ---------------- K0: permuted bf16 hi/mid split; e2; zero loss+cnt ---------
// Output layout (halves): B[t*2048 + buf*512 + lane*8 + j] where for code c,
// dim d: t=c>>4, row=c&15, g=(d&31)>>3, lane=g*16+row, buf=(d<32?0:1) for hi,
// +2 for mid, j=d&7. Hot-loop loads become lane-contiguous 1-KB transactions.
__global__ __launch_bounds__(256) void vqk0(const float* __restrict__ emb,
                                            u32* __restrict__ b32,
                                            float* __restrict__ e2, u32* __restrict__ cnt,
                                            float* __restrict__ out) {
    int gid = blockIdx.x * 256 + threadIdx.x;   // 128 blocks -> 32768 threads
    int c = gid >> 5;
    int d = (gid & 31) * 2;                     // even dim; pair (d, d+1) same group
    float2 v = ((const float2*)emb)[gid];       // coalesced read
    ushort_t h0 = f2bf(v.x), h1 = f2bf(v.y);
    ushort_t m0 = f2bf(v.x - bf2f(h0)), m1 = f2bf(v.y - bf2f(h1));
    int t = c >> 4, row = c & 15;
    int g = (d & 31) >> 3;
    int bh = (d < 32) ? 0 : 1;
    int lane = g * 16 + row;
    int u = t * 1024 + lane * 4 + ((d & 7) >> 1);   // u32 units within tile block
    b32[u + bh * 256]       = (u32)h0 | ((u32)h1 << 16);
    b32[u + (bh + 2) * 256] = (u32)m0 | ((u32)m1 << 16);
    if (gid < NK) {                             // exact f32 |e|^2 (R3 order)
        const float4* e4 = (const float4*)(emb + (long)gid * D);
        float s = 0.f;
#pragma unroll
        for (int i = 0; i < D / 4; ++i) {
            float4 w = e4[i];
            s += w.x * w.x + w.y * w.y + w.z * w.z + w.w * w.w;
        }
        e2[gid] = s;
    }
    if (gid == 0) { out[LOSS_OFF] = 0.0f; *cnt = 0; }
}

#define LDB(P) (*(const bf16x8*)(P))

// One 16-code tile vs TWO query sub-tiles (wave owns 32 queries).
#define COMPUTE_TILE(T, BH0, BH1, BM0, BM1) do {                               \
    const int c_ = (T) * 16 + row;                                             \
    const float h_ = 0.5f * e2l[c_];                                           \
    _Pragma("unroll")                                                          \
    for (int s_ = 0; s_ < 2; ++s_) {                                           \
        f32x4 acc = {0.f, 0.f, 0.f, 0.f};                                      \
        acc = __builtin_amdgcn_mfma_f32_16x16x32_bf16(ah[s_][0], BM0, acc, 0, 0, 0); \
        acc = __builtin_amdgcn_mfma_f32_16x16x32_bf16(am[s_][0], BH0, acc, 0, 0, 0); \
        acc = __builtin_amdgcn_mfma_f32_16x16x32_bf16(ah[s_][0], BH0, acc, 0, 0, 0); \
        acc = __builtin_amdgcn_mfma_f32_16x16x32_bf16(ah[s_][1], BM1, acc, 0, 0, 0); \
        acc = __builtin_amdgcn_mfma_f32_16x16x32_bf16(am[s_][1], BH1, acc, 0, 0, 0); \
        acc = __builtin_amdgcn_mfma_f32_16x16x32_bf16(ah[s_][1], BH1, acc, 0, 0, 0); \
        _Pragma("unroll")                                                      \
        for (int r_ = 0; r_ < 4; ++r_) {                                       \
            int sl_ = s_ * 4 + r_;                                             \
            float sd_ = h_ - acc[r_];                                          \
            float ns2_ = fminf(fmaxf(sd_, s1v[sl_]), s2v[sl_]);   /* med3 */   \
            bool lt_ = sd_ < s1v[sl_];                                         \
            i1v[sl_] = lt_ ? c_ : i1v[sl_];                                    \
            s1v[sl_] = fminf(sd_, s1v[sl_]);                                   \
            s2v[sl_] = ns2_;                                                   \
        }                                                                      \
    }                                                                          \
} while (0)

// ---------------- K1: coarse MFMA top-2 + streaming epilogue ----------------
// 512 blocks x 256 thr (2 blocks/CU, 2 waves/SIMD). Wave owns 32 queries.
// B-frags from the PERMUTED buffer: 4 coalesced 1-KB loads per tile, register
// double-buffered (loads for t+1 issue before tile t's 12 MFMAs). Flagged
// queries (top-2 gap <= MARGIN) listed for the exact fix-up kernel.
__global__ __launch_bounds__(256, 2) void vqk1(const float* __restrict__ x,
                                               const ushort_t* __restrict__ B,
                                               const float* __restrict__ e2g,
                                               const float* __restrict__ emb,
                                               u32* __restrict__ cnt,
                                               int* __restrict__ list,
                                               float* __restrict__ out) {
    __shared__ float e2l[NK];        // 4 KB
    __shared__ int   idx_l[128];
    __shared__ float lred[4];

    const int tid = threadIdx.x;
    const int l = tid & 63;
    const int w = tid >> 6;
    const int qbase = blockIdx.x * 128;
    const int wb = qbase + w * 32;   // wave's first query
    const int row = l & 15;
    const int g = l >> 4;
    const int koff = g * 8;

    ((f32x4*)e2l)[tid] = ((const f32x4*)e2g)[tid];

    // Split this wave's 32 queries into bf16 hi/mid A-frags in-register.
    bf16x8 ah[2][2], am[2][2];
#pragma unroll
    for (int s = 0; s < 2; ++s) {
        const float* xr = x + (long)(wb + s * 16 + row) * D + koff;
#pragma unroll
        for (int half = 0; half < 2; ++half) {
            float4 p0 = ((const float4*)(xr + half * 32))[0];
            float4 p1 = ((const float4*)(xr + half * 32))[1];
            float v[8] = {p0.x, p0.y, p0.z, p0.w, p1.x, p1.y, p1.z, p1.w};
#pragma unroll
            for (int i = 0; i < 8; ++i) {
                ushort_t hs = f2bf(v[i]);
                ushort_t ms = f2bf(v[i] - bf2f(hs));
                ah[s][half][i] = (short)hs;
                am[s][half][i] = (short)ms;
            }
        }
    }
    __syncthreads();

    float s1v[8], s2v[8];
    int i1v[8];
#pragma unroll
    for (int i = 0; i < 8; ++i) { s1v[i] = 3.4e38f; s2v[i] = 3.4e38f; i1v[i] = 0; }

    // ---- main scan: coalesced loads + register double-buffer ----
    int off = l * 8;                 // halves; tile 0 fragment for this lane
    bf16x8 bh0 = LDB(B + off),        bh1 = LDB(B + off + 512);
    bf16x8 bm0 = LDB(B + off + 1024), bm1 = LDB(B + off + 1536);
#pragma unroll 1
    for (int t = 0; t < 64; t += 2) {
        int o1 = off + 2048;                     // tile t+1
        bf16x8 ch0 = LDB(B + o1),        ch1 = LDB(B + o1 + 512);
        bf16x8 cm0 = LDB(B + o1 + 1024), cm1 = LDB(B + o1 + 1536);
        COMPUTE_TILE(t, bh0, bh1, bm0, bm1);
        int o2 = (t == 62) ? (l * 8) : (off + 4096);   // tile t+2 (wrap)
        bh0 = LDB(B + o2);        bh1 = LDB(B + o2 + 512);
        bm0 = LDB(B + o2 + 1024); bm1 = LDB(B + o2 + 1536);
        COMPUTE_TILE(t + 1, ch0, ch1, cm0, cm1);
        off = o2;
    }

    // merge top-2 across the 16 code-columns; lowest index wins exact ties.
#pragma unroll
    for (int d = 1; d < 16; d <<= 1) {
#pragma unroll
        for (int sl = 0; sl < 8; ++sl) {
            float os1 = __shfl_xor(s1v[sl], d, 64);
            float os2 = __shfl_xor(s2v[sl], d, 64);
            int   oi1 = __shfl_xor(i1v[sl], d, 64);
            float hi = s1v[sl] > os1 ? s1v[sl] : os1;
            float lo2 = s2v[sl] < os2 ? s2v[sl] : os2;
            int ni = (os1 < s1v[sl]) ? oi1
                   : ((os1 == s1v[sl] && oi1 < i1v[sl]) ? oi1 : i1v[sl]);
            s1v[sl] = s1v[sl] < os1 ? s1v[sl] : os1;
            s2v[sl] = hi < lo2 ? hi : lo2;
            i1v[sl] = ni;
        }
    }

    if (row == 0) {
#pragma unroll
        for (int sl = 0; sl < 8; ++sl) {
            int s = sl >> 2, r = sl & 3;
            int ql = w * 32 + s * 16 + g * 4 + r;
            idx_l[ql] = i1v[sl];
            if (s2v[sl] - s1v[sl] <= MARGIN) {
                u32 p = atomicAdd(cnt, 1u);
                if (p < CAPQ) list[p] = qbase + ql;
            }
        }
    }
    __syncthreads();

    // ---- streaming epilogue: idx write, gather quantized, loss partial ----
    if (l < 32) out[IDX_OUT_OFF + wb + l] = (float)idx_l[w * 32 + l];

    const f32x4* x4 = (const f32x4*)(x + (long)wb * D);
    const f32x4* e4 = (const f32x4*)emb;
    f32x4* o4 = (f32x4*)(out + (long)wb * D);
    float ls = 0.f;
#pragma unroll 1
    for (int k = 0; k < 8; ++k) {
        int j = l + 64 * k;                      // float4 slot in wave's 2 KB
        int ql = j >> 4;                         // local query for this slot
        int col = j & 15;                        // float4 column within row
        int idx = idx_l[w * 32 + ql];
        f32x4 xv = x4[j];
        f32x4 ev = e4[idx * 16 + col];           // 16 lanes same row: coalesced
        o4[j] = ev;
        f32x4 dd = ev - xv;
        ls += dd[0] * dd[0] + dd[1] * dd[1] + dd[2] * dd[2] + dd[3] * dd[3];
    }
#pragma unroll
    for (int offr = 32; offr > 0; offr >>= 1) ls += __shfl_down(ls, offr, 64);
    if (l == 0) lred[w] = ls;
    __syncthreads();
    if (tid == 0)
        atomicAdd(&out[LOSS_OFF],
                  (lred[0] + lred[1] + lred[2] + lred[3]) * (0.25f / (float)NELEM));
}

// ---------------- K2: exact rescue fix-up (one wave per flagged query) ------
__global__ __launch_bounds__(64) void vqk2(const float* __restrict__ x,
                                           const float* __restrict__ emb,
                                           const float* __restrict__ e2,
                                           const int* __restrict__ list,
                                           const u32* __restrict__ cnt,
                                           float* __restrict__ out) {
    u32 n = *cnt; if (n > CAPQ) n = CAPQ;
    const int l = threadIdx.x;
    for (u32 f = blockIdx.x; f < n; f += gridDim.x) {
        int q = list[f];
        float4 xv[16];
        const float4* xp = (const float4*)(x + (long)q * D);
#pragma unroll
        for (int i = 0; i < 16; ++i) xv[i] = xp[i];
        float best = 3.4e38f; int bi = 0;
#pragma unroll 1
        for (int i = 0; i < 16; ++i) {
            int c = l * 16 + i;                  // lane covers [l*16, l*16+16)
            const float4* ep = (const float4*)(emb + (long)c * D);
            float a0 = 0.f, a1 = 0.f, a2 = 0.f, a3 = 0.f;
#pragma unroll
            for (int k = 0; k < 16; ++k) {
                float4 e = ep[k];
                a0 = fmaf(e.x, xv[k].x, a0); a1 = fmaf(e.y, xv[k].y, a1);
                a2 = fmaf(e.z, xv[k].z, a2); a3 = fmaf(e.w, xv[k].w, a3);
            }
            float s = 0.5f * e2[c] - ((a0 + a1) + (a2 + a3));
            if (s < best) { best = s; bi = c; }  // ascending c: first-min
        }
#pragma unroll
        for (int off = 32; off > 0; off >>= 1) {
            float ob = __shfl_down(best, off, 64);
            int   oi = __shfl_down(bi, off, 64);
            if (ob < best || (ob == best && oi < bi)) { best = ob; bi = oi; }
        }
        bi = __shfl(bi, 0, 64);
        int ci = (int)out[IDX_OUT_OFF + q];      // coarse pick
        if (bi != ci) {
            float xl = x[(long)q * D + l];
            float en = emb[(long)bi * D + l];
            float eo = emb[(long)ci * D + l];
            out[(long)q * D + l] = en;
            float dn = (en - xl) * (en - xl);
            float dol = (eo - xl) * (eo - xl);
            float dd = dn - dol;
#pragma unroll
            for (int off = 32; off > 0; off >>= 1) dd += __shfl_down(dd, off, 64);
            if (l == 0) {
                out[IDX_OUT_OFF + q] = (float)bi;
                atomicAdd(&out[LOSS_OFF], dd * (0.25f / (float)NELEM));
            }
        }
    }
}

// ================== R3 fallback (ws too small) ==============================
#define FDO_CHUNK(B, K) \
    aA0 = fmaf(B[0],  xA[4*K+0].x, aA0); aA1 = fmaf(B[1],  xA[4*K+0].y, aA1); \
    aA2 = fmaf(B[2],  xA[4*K+0].z, aA2); aA3 = fmaf(B[3],  xA[4*K+0].w, aA3); \
    aA0 = fmaf(B[4],  xA[4*K+1].x, aA0); aA1 = fmaf(B[5],  xA[4*K+1].y, aA1); \
    aA2 = fmaf(B[6],  xA[4*K+1].z, aA2); aA3 = fmaf(B[7],  xA[4*K+1].w, aA3); \
    aA0 = fmaf(B[8],  xA[4*K+2].x, aA0); aA1 = fmaf(B[9],  xA[4*K+2].y, aA1); \
    aA2 = fmaf(B[10], xA[4*K+2].z, aA2); aA3 = fmaf(B[11], xA[4*K+2].w, aA3); \
    aA0 = fmaf(B[12], xA[4*K+3].x, aA0); aA1 = fmaf(B[13], xA[4*K+3].y, aA1); \
    aA2 = fmaf(B[14], xA[4*K+3].z, aA2); aA3 = fmaf(B[15], xA[4*K+3].w, aA3); \
    aB0 = fmaf(B[0],  xB[4*K+0].x, aB0); aB1 = fmaf(B[1],  xB[4*K+0].y, aB1); \
    aB2 = fmaf(B[2],  xB[4*K+0].z, aB2); aB3 = fmaf(B[3],  xB[4*K+0].w, aB3); \
    aB0 = fmaf(B[4],  xB[4*K+1].x, aB0); aB1 = fmaf(B[5],  xB[4*K+1].y, aB1); \
    aB2 = fmaf(B[6],  xB[4*K+1].z, aB2); aB3 = fmaf(B[7],  xB[4*K+1].w, aB3); \
    aB0 = fmaf(B[8],  xB[4*K+2].x, aB0); aB1 = fmaf(B[9],  xB[4*K+2].y, aB1); \
    aB2 = fmaf(B[10], xB[4*K+2].z, aB2); aB3 = fmaf(B[11], xB[4*K+2].w, aB3); \
    aB0 = fmaf(B[12], xB[4*K+3].x, aB0); aB1 = fmaf(B[13], xB[4*K+3].y, aB1); \
    aB2 = fmaf(B[14], xB[4*K+3].z, aB2); aB3 = fmaf(B[15], xB[4*K+3].w, aB3);

__global__ __launch_bounds__(256) void vq_e2f(const float* __restrict__ emb,
                                              float* __restrict__ e2,
                                              float* __restrict__ out) {
    int k = blockIdx.x * blockDim.x + threadIdx.x;
    if (k == 0) out[LOSS_OFF] = 0.0f;
    if (k < NK) {
        const float4* e4 = (const float4*)(emb + k * D);
        float s = 0.f;
#pragma unroll
        for (int i = 0; i < D / 4; ++i) {
            float4 v = e4[i];
            s += v.x * v.x + v.y * v.y + v.z * v.z + v.w * v.w;
        }
        e2[k] = s;
    }
}

__global__ __launch_bounds__(256, 2) void vq_mainf(const float* __restrict__ x,
                                                   const float* __restrict__ emb,
                                                   const float* __restrict__ e2g,
                                                   float* __restrict__ out) {
    __shared__ float e2l[NK];
    __shared__ float sm_s[512];
    __shared__ int   sm_c[512];
    const int tid = threadIdx.x;
    const int l = tid & 63;
    const int w = tid >> 6;
    const int qbase = blockIdx.x * 128;
    ((float4*)e2l)[tid] = ((const float4*)e2g)[tid];
    float4 xA[16], xB[16];
    const float4* xpA = (const float4*)(x + (long)(qbase + l) * D);
    const float4* xpB = (const float4*)(x + (long)(qbase + 64 + l) * D);
#pragma unroll
    for (int i = 0; i < 16; ++i) { xA[i] = xpA[i]; xB[i] = xpB[i]; }
    __syncthreads();
    const int code0 = __builtin_amdgcn_readfirstlane(w << 8);
    const float* ep0 = emb + (long)code0 * D;
    float bestA = 3.4e38f, bestB = 3.4e38f;
    int idxA = 0, idxB = 0;
#pragma unroll 1
    for (int g = 0; g < 256; ++g) {
        const float* ep = ep0 + g * D;
        f32x16 b0, b1, b2, b3;
        asm volatile(
            "s_load_dwordx16 %0, %4, 0x0\n\t"
            "s_load_dwordx16 %1, %4, 0x40\n\t"
            "s_load_dwordx16 %2, %4, 0x80\n\t"
            "s_load_dwordx16 %3, %4, 0xC0\n\t"
            "s_waitcnt lgkmcnt(0)"
            : "=s"(b0), "=s"(b1), "=s"(b2), "=s"(b3) : "s"(ep));
        float aA0 = 0.f, aA1 = 0.f, aA2 = 0.f, aA3 = 0.f;
        float aB0 = 0.f, aB1 = 0.f, aB2 = 0.f, aB3 = 0.f;
        FDO_CHUNK(b0, 0) FDO_CHUNK(b1, 1) FDO_CHUNK(b2, 2) FDO_CHUNK(b3, 3)
        float dotA = (aA0 + aA1) + (aA2 + aA3);
        float dotB = (aB0 + aB1) + (aB2 + aB3);
        float e2c = e2l[code0 + g];
        float sA = 0.5f * e2c - dotA;
        float sB = 0.5f * e2c - dotB;
        int code = code0 + g;
        bool lt;
        lt = sA < bestA; bestA = lt ? sA : bestA; idxA = lt ? code : idxA;
        lt = sB < bestB; bestB = lt ? sB : bestB; idxB = lt ? code : idxB;
    }
    sm_s[w * 128 + l] = bestA;      sm_c[w * 128 + l] = idxA;
    sm_s[w * 128 + 64 + l] = bestB; sm_c[w * 128 + 64 + l] = idxB;
    __syncthreads();
    if (tid < 128) {
        float bs = sm_s[tid]; int bc = sm_c[tid];
#pragma unroll
        for (int wv = 1; wv < 4; ++wv) {
            float s = sm_s[wv * 128 + tid]; int c = sm_c[wv * 128 + tid];
            if (s < bs) { bs = s; bc = c; }
        }
        const int q = qbase + tid;
        out[IDX_OUT_OFF + q] = (float)bc;
        const float4* eb = (const float4*)(emb + (long)bc * D);
        const float4* xq = (const float4*)(x + (long)q * D);
        float4* oq = (float4*)(out + (long)q * D);
        float lsum = 0.f;
#pragma unroll
        for (int i = 0; i < 16; ++i) {
            float4 e = eb[i]; float4 xx = xq[i];
            oq[i] = e;
            float dx = e.x - xx.x, dy = e.y - xx.y, dz = e.z - xx.z, dw = e.w - xx.w;
            lsum += dx * dx + dy * dy + dz * dz + dw * dw;
        }
#pragma unroll
        for (int o = 32; o > 0; o >>= 1) lsum += __shfl_down(lsum, o, 64);
        if ((tid & 63) == 0) atomicAdd(&out[LOSS_OFF], lsum * (0.25f / (float)NELEM));
    }
}

extern "C" void kernel_launch(void* const* d_in, const int* in_sizes, int n_in,
                              void* d_out, int out_size, void* d_ws, size_t ws_size,
                              hipStream_t stream) {
    const float* x   = (const float*)d_in[0];
    const float* emb = (const float*)d_in[1];
    float* out = (float*)d_out;
    char* ws = (char*)d_ws;

    if (ws_size < (size_t)WS_NEED) {           // fallback: proven R3 path
        float* e2 = (float*)ws;
        vq_e2f<<<4, 256, 0, stream>>>(emb, e2, out);
        vq_mainf<<<QTOTAL / 128, 256, 0, stream>>>(x, emb, e2, out);
        return;
    }

    float* e2    = (float*)(ws + WS_E2);
    ushort_t* B  = (ushort_t*)(ws + WS_B);
    u32* cnt     = (u32*)(ws + WS_CNT);
    int* list    = (int*)(ws + WS_LIST);

    vqk0<<<128, 256, 0, stream>>>(emb, (u32*)B, e2, cnt, out);
    vqk1<<<QTOTAL / 128, 256, 0, stream>>>(x, B, e2, emb, cnt, list, out);
    vqk2<<<256, 64, 0, stream>>>(x, emb, e2, list, cnt, out);
}

// Round 12
// 121.723 us; speedup vs baseline: 1.3515x; 1.0396x over previous
//
#include <hip/hip_runtime.h>

#define D 64
#define NK 1024
#define QTOTAL 65536
#define NELEM (QTOTAL * D)
#define LOSS_OFF 4194304
#define IDX_OUT_OFF 4194305
#define CAPQ 16384
#define MARGIN 2.0e-3f

typedef float f32x16 __attribute__((ext_vector_type(16)));
typedef short bf16x8 __attribute__((ext_vector_type(8)));
typedef float f32x4 __attribute__((ext_vector_type(4)));
typedef unsigned int u32;
typedef unsigned short ushort_t;

// ---- ws layout (bytes) ----
#define WS_E2   0          // 1024 f32
#define WS_B    4096       // 256 KB permuted bf16 codebook: [tile][H0|H1|M0|M1][lane][8]
#define WS_CNT  266240     // u32 (+pad)
#define WS_LIST 266496     // 16384 i32
#define WS_NEED 332032

__device__ __forceinline__ ushort_t f2bf(float f) {
    u32 u = __float_as_uint(f);
    return (ushort_t)((u + 0x7FFFu + ((u >> 16) & 1u)) >> 16);
}
__device__ __forceinline__ float bf2f(ushort_t h) {
    return __uint_as_float(((u32)h) << 16);
}

// ---------------- K0: permuted bf16 hi/mid split; e2; zero loss+cnt ---------
// B[t*4096B + buf*1024B + lane*16B + j*2B]: coalesced MFMA-fragment order.
__global__ __launch_bounds__(256) void vqk0(const float* __restrict__ emb,
                                            u32* __restrict__ b32,
                                            float* __restrict__ e2, u32* __restrict__ cnt,
                                            float* __restrict__ out) {
    int gid = blockIdx.x * 256 + threadIdx.x;   // 128 blocks -> 32768 threads
    int c = gid >> 5;
    int d = (gid & 31) * 2;                     // even dim; pair (d, d+1) same group
    float2 v = ((const float2*)emb)[gid];       // coalesced read
    ushort_t h0 = f2bf(v.x), h1 = f2bf(v.y);
    ushort_t m0 = f2bf(v.x - bf2f(h0)), m1 = f2bf(v.y - bf2f(h1));
    int t = c >> 4, row = c & 15;
    int g = (d & 31) >> 3;
    int bh = (d < 32) ? 0 : 1;
    int lane = g * 16 + row;
    int u = t * 1024 + lane * 4 + ((d & 7) >> 1);   // u32 units within tile block
    b32[u + bh * 256]       = (u32)h0 | ((u32)h1 << 16);
    b32[u + (bh + 2) * 256] = (u32)m0 | ((u32)m1 << 16);
    if (gid < NK) {                             // exact f32 |e|^2 (R3 order)
        const float4* e4 = (const float4*)(emb + (long)gid * D);
        float s = 0.f;
#pragma unroll
        for (int i = 0; i < D / 4; ++i) {
            float4 w = e4[i];
            s += w.x * w.x + w.y * w.y + w.z * w.z + w.w * w.w;
        }
        e2[gid] = s;
    }
    if (gid == 0) { out[LOSS_OFF] = 0.0f; *cnt = 0; }
}

// One 16-code tile vs TWO query sub-tiles (wave owns 32 queries).
// e2l holds 0.5*|e|^2 (pre-scaled at fill; exact).
#define COMPUTE_TILE(T, BH0, BH1, BM0, BM1) do {                               \
    const int c_ = (T) * 16 + row;                                             \
    const float h_ = e2l[c_];                                                  \
    _Pragma("unroll")                                                          \
    for (int s_ = 0; s_ < 2; ++s_) {                                           \
        f32x4 acc = {0.f, 0.f, 0.f, 0.f};                                      \
        acc = __builtin_amdgcn_mfma_f32_16x16x32_bf16(ah[s_][0], BM0, acc, 0, 0, 0); \
        acc = __builtin_amdgcn_mfma_f32_16x16x32_bf16(am[s_][0], BH0, acc, 0, 0, 0); \
        acc = __builtin_amdgcn_mfma_f32_16x16x32_bf16(ah[s_][0], BH0, acc, 0, 0, 0); \
        acc = __builtin_amdgcn_mfma_f32_16x16x32_bf16(ah[s_][1], BM1, acc, 0, 0, 0); \
        acc = __builtin_amdgcn_mfma_f32_16x16x32_bf16(am[s_][1], BH1, acc, 0, 0, 0); \
        acc = __builtin_amdgcn_mfma_f32_16x16x32_bf16(ah[s_][1], BH1, acc, 0, 0, 0); \
        _Pragma("unroll")                                                      \
        for (int r_ = 0; r_ < 4; ++r_) {                                       \
            int sl_ = s_ * 4 + r_;                                             \
            float sd_ = h_ - acc[r_];                                          \
            float ns2_ = fminf(fmaxf(sd_, s1v[sl_]), s2v[sl_]);   /* med3 */   \
            bool lt_ = sd_ < s1v[sl_];                                         \
            i1v[sl_] = lt_ ? c_ : i1v[sl_];                                    \
            s1v[sl_] = fminf(sd_, s1v[sl_]);                                   \
            s2v[sl_] = ns2_;                                                   \
        }                                                                      \
    }                                                                          \
} while (0)

// Read tile frag (4 x bf16x8) for local tile tt from LDS stage buffer.
#define LDS_FRAG(SB, TT, H0, H1, M0, M1) do {                                  \
    const ushort_t* p_ = (SB) + (TT) * 2048 + l * 8;                           \
    H0 = *(const bf16x8*)(p_);                                                 \
    H1 = *(const bf16x8*)(p_ + 512);                                           \
    M0 = *(const bf16x8*)(p_ + 1024);                                          \
    M1 = *(const bf16x8*)(p_ + 1536);                                          \
} while (0)

// ---------------- K1: LDS-staged coarse MFMA top-2 + streaming epilogue -----
// 512 blocks x 256 thr (2 blocks/CU, 2 waves/SIMD). Wave owns 32 queries.
// Codebook staged through LDS in 16-KB chunks (4 tiles), double-buffered:
// global loads for chunk c+1 issue at top of chunk c (latency hidden under
// ~1900 cyc of compute, drained only at the ds_write before the barrier).
// Hot loop reads conflict-free ds_read_b128 with one-tile register prefetch.
__global__ __launch_bounds__(256, 2) void vqk1(const float* __restrict__ x,
                                               const ushort_t* __restrict__ B,
                                               const float* __restrict__ e2g,
                                               const float* __restrict__ emb,
                                               u32* __restrict__ cnt,
                                               int* __restrict__ list,
                                               float* __restrict__ out) {
    __shared__ f32x4 stage[2][1024];  // 2 x 16 KB chunk buffers
    __shared__ float e2l[NK];         // 4 KB (holds 0.5*|e|^2)
    __shared__ int   idx_l[128];
    __shared__ float lred[4];

    const int tid = threadIdx.x;
    const int l = tid & 63;
    const int w = tid >> 6;
    const int qbase = blockIdx.x * 128;
    const int wb = qbase + w * 32;   // wave's first query
    const int row = l & 15;
    const int g = l >> 4;
    const int koff = g * 8;

    {   // e2 -> LDS, pre-scaled by 0.5 (exact)
        f32x4 t = ((const f32x4*)e2g)[tid];
        ((f32x4*)e2l)[tid] = t * 0.5f;
    }

    // Split this wave's 32 queries into bf16 hi/mid A-frags in-register.
    bf16x8 ah[2][2], am[2][2];
#pragma unroll
    for (int s = 0; s < 2; ++s) {
        const float* xr = x + (long)(wb + s * 16 + row) * D + koff;
#pragma unroll
        for (int half = 0; half < 2; ++half) {
            float4 p0 = ((const float4*)(xr + half * 32))[0];
            float4 p1 = ((const float4*)(xr + half * 32))[1];
            float v[8] = {p0.x, p0.y, p0.z, p0.w, p1.x, p1.y, p1.z, p1.w};
#pragma unroll
            for (int i = 0; i < 8; ++i) {
                ushort_t hs = f2bf(v[i]);
                ushort_t ms = f2bf(v[i] - bf2f(hs));
                ah[s][half][i] = (short)hs;
                am[s][half][i] = (short)ms;
            }
        }
    }

    float s1v[8], s2v[8];
    int i1v[8];
#pragma unroll
    for (int i = 0; i < 8; ++i) { s1v[i] = 3.4e38f; s2v[i] = 3.4e38f; i1v[i] = 0; }

    const f32x4* gB = (const f32x4*)B;   // 16-B units; tile = 256 units

    // ---- prologue: stage chunk 0 ----
    {
        f32x4 st0[4];
#pragma unroll
        for (int tt = 0; tt < 4; ++tt) st0[tt] = gB[tt * 256 + tid];
#pragma unroll
        for (int tt = 0; tt < 4; ++tt) stage[0][tt * 256 + tid] = st0[tt];
    }
    __syncthreads();

    // ---- main scan: 16 chunks x 4 tiles ----
#pragma unroll 1
    for (int c = 0; c < 16; ++c) {
        const int cb = c & 1;
        const ushort_t* sb = (const ushort_t*)&stage[cb][0];

        // issue global loads for chunk c+1 (consumed ~1900 cyc later)
        f32x4 st[4];
        if (c < 15) {
#pragma unroll
            for (int tt = 0; tt < 4; ++tt)
                st[tt] = gB[(c + 1) * 1024 + tt * 256 + tid];
        }

        // compute 4 tiles with one-tile-ahead LDS register prefetch
        bf16x8 bh0, bh1, bm0, bm1, nh0, nh1, nm0, nm1;
        LDS_FRAG(sb, 0, bh0, bh1, bm0, bm1);
#pragma unroll
        for (int tt = 0; tt < 4; ++tt) {
            if (tt < 3) LDS_FRAG(sb, tt + 1, nh0, nh1, nm0, nm1);
            COMPUTE_TILE(c * 4 + tt, bh0, bh1, bm0, bm1);
            bh0 = nh0; bh1 = nh1; bm0 = nm0; bm1 = nm1;
        }

        // write staged chunk into the other buffer, then barrier
        if (c < 15) {
#pragma unroll
            for (int tt = 0; tt < 4; ++tt)
                stage[cb ^ 1][tt * 256 + tid] = st[tt];
        }
        __syncthreads();
    }

    // merge top-2 across the 16 code-columns; lowest index wins exact ties.
#pragma unroll
    for (int d = 1; d < 16; d <<= 1) {
#pragma unroll
        for (int sl = 0; sl < 8; ++sl) {
            float os1 = __shfl_xor(s1v[sl], d, 64);
            float os2 = __shfl_xor(s2v[sl], d, 64);
            int   oi1 = __shfl_xor(i1v[sl], d, 64);
            float hi = s1v[sl] > os1 ? s1v[sl] : os1;
            float lo2 = s2v[sl] < os2 ? s2v[sl] : os2;
            int ni = (os1 < s1v[sl]) ? oi1
                   : ((os1 == s1v[sl] && oi1 < i1v[sl]) ? oi1 : i1v[sl]);
            s1v[sl] = s1v[sl] < os1 ? s1v[sl] : os1;
            s2v[sl] = hi < lo2 ? hi : lo2;
            i1v[sl] = ni;
        }
    }

    if (row == 0) {
#pragma unroll
        for (int sl = 0; sl < 8; ++sl) {
            int s = sl >> 2, r = sl & 3;
            int ql = w * 32 + s * 16 + g * 4 + r;
            idx_l[ql] = i1v[sl];
            if (s2v[sl] - s1v[sl] <= MARGIN) {
                u32 p = atomicAdd(cnt, 1u);
                if (p < CAPQ) list[p] = qbase + ql;
            }
        }
    }
    __syncthreads();

    // ---- streaming epilogue: idx write, gather quantized, loss partial ----
    if (l < 32) out[IDX_OUT_OFF + wb + l] = (float)idx_l[w * 32 + l];

    const f32x4* x4 = (const f32x4*)(x + (long)wb * D);
    const f32x4* e4 = (const f32x4*)emb;
    f32x4* o4 = (f32x4*)(out + (long)wb * D);
    float ls = 0.f;
#pragma unroll 1
    for (int k = 0; k < 8; ++k) {
        int j = l + 64 * k;                      // float4 slot in wave's 2 KB
        int ql = j >> 4;                         // local query for this slot
        int col = j & 15;                        // float4 column within row
        int idx = idx_l[w * 32 + ql];
        f32x4 xv = x4[j];
        f32x4 ev = e4[idx * 16 + col];           // 16 lanes same row: coalesced
        o4[j] = ev;
        f32x4 dd = ev - xv;
        ls += dd[0] * dd[0] + dd[1] * dd[1] + dd[2] * dd[2] + dd[3] * dd[3];
    }
#pragma unroll
    for (int offr = 32; offr > 0; offr >>= 1) ls += __shfl_down(ls, offr, 64);
    if (l == 0) lred[w] = ls;
    __syncthreads();
    if (tid == 0)
        atomicAdd(&out[LOSS_OFF],
                  (lred[0] + lred[1] + lred[2] + lred[3]) * (0.25f / (float)NELEM));
}

// ---------------- K2: exact rescue fix-up (one wave per flagged query) ------
__global__ __launch_bounds__(64) void vqk2(const float* __restrict__ x,
                                           const float* __restrict__ emb,
                                           const float* __restrict__ e2,
                                           const int* __restrict__ list,
                                           const u32* __restrict__ cnt,
                                           float* __restrict__ out) {
    u32 n = *cnt; if (n > CAPQ) n = CAPQ;
    const int l = threadIdx.x;
    for (u32 f = blockIdx.x; f < n; f += gridDim.x) {
        int q = list[f];
        float4 xv[16];
        const float4* xp = (const float4*)(x + (long)q * D);
#pragma unroll
        for (int i = 0; i < 16; ++i) xv[i] = xp[i];
        float best = 3.4e38f; int bi = 0;
#pragma unroll 1
        for (int i = 0; i < 16; ++i) {
            int c = l * 16 + i;                  // lane covers [l*16, l*16+16)
            const float4* ep = (const float4*)(emb + (long)c * D);
            float a0 = 0.f, a1 = 0.f, a2 = 0.f, a3 = 0.f;
#pragma unroll
            for (int k = 0; k < 16; ++k) {
                float4 e = ep[k];
                a0 = fmaf(e.x, xv[k].x, a0); a1 = fmaf(e.y, xv[k].y, a1);
                a2 = fmaf(e.z, xv[k].z, a2); a3 = fmaf(e.w, xv[k].w, a3);
            }
            float s = 0.5f * e2[c] - ((a0 + a1) + (a2 + a3));
            if (s < best) { best = s; bi = c; }  // ascending c: first-min
        }
#pragma unroll
        for (int off = 32; off > 0; off >>= 1) {
            float ob = __shfl_down(best, off, 64);
            int   oi = __shfl_down(bi, off, 64);
            if (ob < best || (ob == best && oi < bi)) { best = ob; bi = oi; }
        }
        bi = __shfl(bi, 0, 64);
        int ci = (int)out[IDX_OUT_OFF + q];      // coarse pick
        if (bi != ci) {
            float xl = x[(long)q * D + l];
            float en = emb[(long)bi * D + l];
            float eo = emb[(long)ci * D + l];
            out[(long)q * D + l] = en;
            float dn = (en - xl) * (en - xl);
            float dol = (eo - xl) * (eo - xl);
            float dd = dn - dol;
#pragma unroll
            for (int off = 32; off > 0; off >>= 1) dd += __shfl_down(dd, off, 64);
            if (l == 0) {
                out[IDX_OUT_OFF + q] = (float)bi;
                atomicAdd(&out[LOSS_OFF], dd * (0.25f / (float)NELEM));
            }
        }
    }
}

// ================== R3 fallback (ws too small) ==============================
#define FDO_CHUNK(B, K) \
    aA0 = fmaf(B[0],  xA[4*K+0].x, aA0); aA1 = fmaf(B[1],  xA[4*K+0].y, aA1); \
    aA2 = fmaf(B[2],  xA[4*K+0].z, aA2); aA3 = fmaf(B[3],  xA[4*K+0].w, aA3); \
    aA0 = fmaf(B[4],  xA[4*K+1].x, aA0); aA1 = fmaf(B[5],  xA[4*K+1].y, aA1); \
    aA2 = fmaf(B[6],  xA[4*K+1].z, aA2); aA3 = fmaf(B[7],  xA[4*K+1].w, aA3); \
    aA0 = fmaf(B[8],  xA[4*K+2].x, aA0); aA1 = fmaf(B[9],  xA[4*K+2].y, aA1); \
    aA2 = fmaf(B[10], xA[4*K+2].z, aA2); aA3 = fmaf(B[11], xA[4*K+2].w, aA3); \
    aA0 = fmaf(B[12], xA[4*K+3].x, aA0); aA1 = fmaf(B[13], xA[4*K+3].y, aA1); \
    aA2 = fmaf(B[14], xA[4*K+3].z, aA2); aA3 = fmaf(B[15], xA[4*K+3].w, aA3); \
    aB0 = fmaf(B[0],  xB[4*K+0].x, aB0); aB1 = fmaf(B[1],  xB[4*K+0].y, aB1); \
    aB2 = fmaf(B[2],  xB[4*K+0].z, aB2); aB3 = fmaf(B[3],  xB[4*K+0].w, aB3); \
    aB0 = fmaf(B[4],  xB[4*K+1].x, aB0); aB1 = fmaf(B[5],  xB[4*K+1].y, aB1); \
    aB2 = fmaf(B[6],  xB[4*K+1].z, aB2); aB3 = fmaf(B[7],  xB[4*K+1].w, aB3); \
    aB0 = fmaf(B[8],  xB[4*K+2].x, aB0); aB1 = fmaf(B[9],  xB[4*K+2].y, aB1); \
    aB2 = fmaf(B[10], xB[4*K+2].z, aB2); aB3 = fmaf(B[11], xB[4*K+2].w, aB3); \
    aB0 = fmaf(B[12], xB[4*K+3].x, aB0); aB1 = fmaf(B[13], xB[4*K+3].y, aB1); \
    aB2 = fmaf(B[14], xB[4*K+3].z, aB2); aB3 = fmaf(B[15], xB[4*K+3].w, aB3);

__global__ __launch_bounds__(256) void vq_e2f(const float* __restrict__ emb,
                                              float* __restrict__ e2,
                                              float* __restrict__ out) {
    int k = blockIdx.x * blockDim.x + threadIdx.x;
    if (k == 0) out[LOSS_OFF] = 0.0f;
    if (k < NK) {
        const float4* e4 = (const float4*)(emb + k * D);
        float s = 0.f;
#pragma unroll
        for (int i = 0; i < D / 4; ++i) {
            float4 v = e4[i];
            s += v.x * v.x + v.y * v.y + v.z * v.z + v.w * v.w;
        }
        e2[k] = s;
    }
}

__global__ __launch_bounds__(256, 2) void vq_mainf(const float* __restrict__ x,
                                                   const float* __restrict__ emb,
                                                   const float* __restrict__ e2g,
                                                   float* __restrict__ out) {
    __shared__ float e2l[NK];
    __shared__ float sm_s[512];
    __shared__ int   sm_c[512];
    const int tid = threadIdx.x;
    const int l = tid & 63;
    const int w = tid >> 6;
    const int qbase = blockIdx.x * 128;
    ((float4*)e2l)[tid] = ((const float4*)e2g)[tid];
    float4 xA[16], xB[16];
    const float4* xpA = (const float4*)(x + (long)(qbase + l) * D);
    const float4* xpB = (const float4*)(x + (long)(qbase + 64 + l) * D);
#pragma unroll
    for (int i = 0; i < 16; ++i) { xA[i] = xpA[i]; xB[i] = xpB[i]; }
    __syncthreads();
    const int code0 = __builtin_amdgcn_readfirstlane(w << 8);
    const float* ep0 = emb + (long)code0 * D;
    float bestA = 3.4e38f, bestB = 3.4e38f;
    int idxA = 0, idxB = 0;
#pragma unroll 1
    for (int g = 0; g < 256; ++g) {
        const float* ep = ep0 + g * D;
        f32x16 b0, b1, b2, b3;
        asm volatile(
            "s_load_dwordx16 %0, %4, 0x0\n\t"
            "s_load_dwordx16 %1, %4, 0x40\n\t"
            "s_load_dwordx16 %2, %4, 0x80\n\t"
            "s_load_dwordx16 %3, %4, 0xC0\n\t"
            "s_waitcnt lgkmcnt(0)"
            : "=s"(b0), "=s"(b1), "=s"(b2), "=s"(b3) : "s"(ep));
        float aA0 = 0.f, aA1 = 0.f, aA2 = 0.f, aA3 = 0.f;
        float aB0 = 0.f, aB1 = 0.f, aB2 = 0.f, aB3 = 0.f;
        FDO_CHUNK(b0, 0) FDO_CHUNK(b1, 1) FDO_CHUNK(b2, 2) FDO_CHUNK(b3, 3)
        float dotA = (aA0 + aA1) + (aA2 + aA3);
        float dotB = (aB0 + aB1) + (aB2 + aB3);
        float e2c = e2l[code0 + g];
        float sA = 0.5f * e2c - dotA;
        float sB = 0.5f * e2c - dotB;
        int code = code0 + g;
        bool lt;
        lt = sA < bestA; bestA = lt ? sA : bestA; idxA = lt ? code : idxA;
        lt = sB < bestB; bestB = lt ? sB : bestB; idxB = lt ? code : idxB;
    }
    sm_s[w * 128 + l] = bestA;      sm_c[w * 128 + l] = idxA;
    sm_s[w * 128 + 64 + l] = bestB; sm_c[w * 128 + 64 + l] = idxB;
    __syncthreads();
    if (tid < 128) {
        float bs = sm_s[tid]; int bc = sm_c[tid];
#pragma unroll
        for (int wv = 1; wv < 4; ++wv) {
            float s = sm_s[wv * 128 + tid]; int c = sm_c[wv * 128 + tid];
            if (s < bs) { bs = s; bc = c; }
        }
        const int q = qbase + tid;
        out[IDX_OUT_OFF + q] = (float)bc;
        const float4* eb = (const float4*)(emb + (long)bc * D);
        const float4* xq = (const float4*)(x + (long)q * D);
        float4* oq = (float4*)(out + (long)q * D);
        float lsum = 0.f;
#pragma unroll
        for (int i = 0; i < 16; ++i) {
            float4 e = eb[i]; float4 xx = xq[i];
            oq[i] = e;
            float dx = e.x - xx.x, dy = e.y - xx.y, dz = e.z - xx.z, dw = e.w - xx.w;
            lsum += dx * dx + dy * dy + dz * dz + dw * dw;
        }
#pragma unroll
        for (int o = 32; o > 0; o >>= 1) lsum += __shfl_down(lsum, o, 64);
        if ((tid & 63) == 0) atomicAdd(&out[LOSS_OFF], lsum * (0.25f / (float)NELEM));
    }
}

extern "C" void kernel_launch(void* const* d_in, const int* in_sizes, int n_in,
                              void* d_out, int out_size, void* d_ws, size_t ws_size,
                              hipStream_t stream) {
    const float* x   = (const float*)d_in[0];
    const float* emb = (const float*)d_in[1];
    float* out = (float*)d_out;
    char* ws = (char*)d_ws;

    if (ws_size < (size_t)WS_NEED) {           // fallback: proven R3 path
        float* e2 = (float*)ws;
        vq_e2f<<<4, 256, 0, stream>>>(emb, e2, out);
        vq_mainf<<<QTOTAL / 128, 256, 0, stream>>>(x, emb, e2, out);
        return;
    }

    float* e2    = (float*)(ws + WS_E2);
    ushort_t* B  = (ushort_t*)(ws + WS_B);
    u32* cnt     = (u32*)(ws + WS_CNT);
    int* list    = (int*)(ws + WS_LIST);

    vqk0<<<128, 256, 0, stream>>>(emb, (u32*)B, e2, cnt, out);
    vqk1<<<QTOTAL / 128, 256, 0, stream>>>(x, B, e2, emb, cnt, list, out);
    vqk2<<<256, 64, 0, stream>>>(x, emb, e2, list, cnt, out);
}